// Round 9
// baseline (187.394 us; speedup 1.0000x reference)
//
#include <hip/hip_runtime.h>

// Sobel 3D magnitude, separable: S=[1,2,1], D=[1,0,-1]
// gx = Sz(Sy(Dx)), gy = Sz(Dy(Sx)), gz = Dz(Sy(Sx)); out = sqrt(gx^2+gy^2+gz^2+1e-6)
// x: (2,32,64,128,128) fp32.
// R9 = R7 (no LDS/barriers, 3 independent row loads/plane, y-pass-first,
// 4 shuffles/plane, marching pointers, single body/emit) + depth-2 prefetch:
// two in-flight row TRIPLES p,q (no cross-lane coupling), roll p<-q, q<-new.
// Load-to-use distance = 2 iterations to cover ~900-cycle HBM latency.

typedef float floatx4 __attribute__((ext_vector_type(4)));

constexpr int W   = 128;
constexpr int H   = 128;
constexpr int DZ  = 64;
constexpr int NC  = 2 * 32;
constexpr int TH  = 8;            // output rows per block
constexpr int HBLKS = H / TH;     // 16
constexpr int ZCH = 2;            // z chunks
constexpr int ZLEN = DZ / ZCH;    // 32

__global__ __launch_bounds__(256, 6)
void sobel3d_kernel(const float* __restrict__ xg, float* __restrict__ og) {
    const int tid = threadIdx.x;
    const int tx  = tid & 31;      // w segment: pixels 4*tx..4*tx+3
    const int ty  = tid >> 5;      // row 0..7 within tile
    int b = blockIdx.x;
    const int hblk = b % HBLKS; b /= HBLKS;
    const int zc   = b % ZCH;   b /= ZCH;
    const int nc   = b;
    const int h    = hblk * TH + ty;
    const int za   = zc * ZLEN;
    const int zb   = za + ZLEN;                  // exclusive
    const int lastv = (zb < DZ) ? zb : DZ - 1;   // last loadable plane index

    const size_t HW = (size_t)H * W;
    const float* __restrict__ xp = xg + (size_t)nc * DZ * HW;
    float* __restrict__ op       = og + (size_t)nc * DZ * HW;

    const bool hm = (h > 0);
    const bool hp = (h < H - 1);
    const size_t roff = (size_t)h * W + 4 * tx;

    // rows h-1,h,h+1 at pointer p (plane base + roff); ±W fold to imm offsets
    auto load3 = [&](const float* p, floatx4& a, floatx4& bq, floatx4& c) {
        a  = hm ? *(const floatx4*)(p - W) : (floatx4){0.f, 0.f, 0.f, 0.f};
        bq = *(const floatx4*)p;
        c  = hp ? *(const floatx4*)(p + W) : (floatx4){0.f, 0.f, 0.f, 0.f};
    };

    // y-pass first (no shuffles), then x-pass on u=Sy(x), v=Dy(x).
    // cc = Sx(Sy), dd = Dy(Sx), ee = Dx(Sy)  (axes commute)
    auto plane_sde = [&](floatx4 qA, floatx4 qB, floatx4 qC,
                         floatx4& cc, floatx4& dd, floatx4& ee) {
        floatx4 u = qA + 2.f * qB + qC;
        floatx4 v = qA - qC;
        float um1 = __shfl_up(u.w, 1, 64);   if (tx == 0)  um1 = 0.f;
        float up4 = __shfl_down(u.x, 1, 64); if (tx == 31) up4 = 0.f;
        float vm1 = __shfl_up(v.w, 1, 64);   if (tx == 0)  vm1 = 0.f;
        float vp4 = __shfl_down(v.x, 1, 64); if (tx == 31) vp4 = 0.f;
        cc.x = um1 + 2.f * u.x + u.y;
        cc.y = u.x + 2.f * u.y + u.z;
        cc.z = u.y + 2.f * u.z + u.w;
        cc.w = u.z + 2.f * u.w + up4;
        ee.x = um1 - u.y;                 // Dx(u): reuses u's shuffled halos
        ee.y = u.x - u.z;
        ee.z = u.y - u.w;
        ee.w = u.z - up4;
        dd.x = vm1 + 2.f * v.x + v.y;
        dd.y = v.x + 2.f * v.y + v.z;
        dd.z = v.y + 2.f * v.z + v.w;
        dd.w = v.z + 2.f * v.w + vp4;
    };

    // rolling 2-plane intermediates: P = plane z-1, C = plane z
    floatx4 cP, dP, eP, cC, dCv, eC;
    const float* pin = xp + (size_t)za * HW + roff;   // plane za
    {
        floatx4 a, bq, c;
        if (za > 0) { load3(pin - HW, a, bq, c); plane_sde(a, bq, c, cP, dP, eP); }
        else        { cP = dP = eP = (floatx4){0.f, 0.f, 0.f, 0.f}; }
        load3(pin, a, bq, c); plane_sde(a, bq, c, cC, dCv, eC);
    }
    // depth-2 prefetch: p = rows of plane za+1, q = rows of plane za+2
    floatx4 pA, pB, pC, qA, qB, qC;
    load3(pin + HW,     pA, pB, pC);
    load3(pin + 2 * HW, qA, qB, qC);
    pin += 3 * HW;                                    // -> plane za+3
    float* pout = op + (size_t)za * HW + roff;

#pragma unroll 2
    for (int z = za; z < zb; ++z) {
        // prefetch plane z+3 (wave-uniform validity; beyond need -> zeros)
        floatx4 nA, nB, nC;
        if (z + 3 <= lastv) load3(pin, nA, nB, nC);
        else { nA = nB = nC = (floatx4){0.f, 0.f, 0.f, 0.f}; }
        pin += HW;

        // compute plane z+1 intermediates (rows prefetched 2 iterations ago)
        floatx4 c2, d2, e2;
        plane_sde(pA, pB, pC, c2, d2, e2);

        // emit output plane z
        floatx4 gx = eP + 2.f * eC + e2;
        floatx4 gy = dP + 2.f * dCv + d2;
        floatx4 gz = cP - c2;
        floatx4 o;
        o.x = __builtin_amdgcn_sqrtf(gx.x * gx.x + gy.x * gy.x + gz.x * gz.x + 1e-6f);
        o.y = __builtin_amdgcn_sqrtf(gx.y * gx.y + gy.y * gy.y + gz.y * gz.y + 1e-6f);
        o.z = __builtin_amdgcn_sqrtf(gx.z * gx.z + gy.z * gy.z + gz.z * gz.z + 1e-6f);
        o.w = __builtin_amdgcn_sqrtf(gx.w * gx.w + gy.w * gy.w + gz.w * gz.w + 1e-6f);
        __builtin_nontemporal_store(o, (floatx4*)pout);
        pout += HW;

        // roll windows (renamed by unroll 2)
        cP = cC;  cC  = c2;
        dP = dCv; dCv = d2;
        eP = eC;  eC  = e2;
        pA = qA;  pB  = qB;  pC = qC;
        qA = nA;  qB  = nB;  qC = nC;
    }
}

extern "C" void kernel_launch(void* const* d_in, const int* in_sizes, int n_in,
                              void* d_out, int out_size, void* d_ws, size_t ws_size,
                              hipStream_t stream) {
    const float* x = (const float*)d_in[0];
    float* out = (float*)d_out;
    dim3 grid(NC * ZCH * HBLKS);   // 2048 blocks == full 8-blocks/CU residency
    dim3 block(256);
    sobel3d_kernel<<<grid, block, 0, stream>>>(x, out);
}

// Round 10
// 107.701 us; speedup vs baseline: 1.7399x; 1.7399x over previous
//
#include <hip/hip_runtime.h>

// Sobel 3D magnitude, separable: S=[1,2,1], D=[1,0,-1]
// gx = Sz(Sy(Dx)), gy = Sz(Dy(Sx)), gz = Dz(Sy(Sx)); out = sqrt(gx^2+gy^2+gz^2+1e-6)
// x: (2,32,64,128,128) fp32.
// R10 = R7 + depth-2 prefetch, spill-proofed:
//   - NO unroll pragma (R9 suspect: unroll-2 doubled live ranges)
//   - branch-free prefetch: clamped always-valid pointer, loads issue
//     unconditionally (R9 suspect: if/else phi pinned 12 regs through merge)
//   - __launch_bounds__(256,4): explicit 128-VGPR budget, no allocator panic
// Tripwire: WRITE_SIZE must stay exactly 262144 KB (no scratch).

typedef float floatx4 __attribute__((ext_vector_type(4)));

constexpr int W   = 128;
constexpr int H   = 128;
constexpr int DZ  = 64;
constexpr int NC  = 2 * 32;
constexpr int TH  = 8;            // output rows per block
constexpr int HBLKS = H / TH;     // 16
constexpr int ZCH = 2;            // z chunks
constexpr int ZLEN = DZ / ZCH;    // 32

__global__ __launch_bounds__(256, 4)
void sobel3d_kernel(const float* __restrict__ xg, float* __restrict__ og) {
    const int tid = threadIdx.x;
    const int tx  = tid & 31;      // w segment: pixels 4*tx..4*tx+3
    const int ty  = tid >> 5;      // row 0..7 within tile
    int b = blockIdx.x;
    const int hblk = b % HBLKS; b /= HBLKS;
    const int zc   = b % ZCH;   b /= ZCH;
    const int nc   = b;
    const int h    = hblk * TH + ty;
    const int za   = zc * ZLEN;
    const int zb   = za + ZLEN;                  // exclusive
    const int lastv = (zb < DZ) ? zb : DZ - 1;   // last loadable plane index

    const size_t HW = (size_t)H * W;
    const float* __restrict__ xp = xg + (size_t)nc * DZ * HW;
    float* __restrict__ op       = og + (size_t)nc * DZ * HW;

    const bool hm = (h > 0);
    const bool hp = (h < H - 1);
    const size_t roff = (size_t)h * W + 4 * tx;

    // rows h-1,h,h+1 at pointer p (plane base + roff); ±W fold to imm offsets
    auto load3 = [&](const float* p, floatx4& a, floatx4& bq, floatx4& c) {
        a  = hm ? *(const floatx4*)(p - W) : (floatx4){0.f, 0.f, 0.f, 0.f};
        bq = *(const floatx4*)p;
        c  = hp ? *(const floatx4*)(p + W) : (floatx4){0.f, 0.f, 0.f, 0.f};
    };

    // y-pass first (no shuffles), then x-pass on u=Sy(x), v=Dy(x).
    // cc = Sx(Sy), dd = Dy(Sx), ee = Dx(Sy)  (axes commute)
    auto plane_sde = [&](floatx4 qA, floatx4 qB, floatx4 qC,
                         floatx4& cc, floatx4& dd, floatx4& ee) {
        floatx4 u = qA + 2.f * qB + qC;
        floatx4 v = qA - qC;
        float um1 = __shfl_up(u.w, 1, 64);   if (tx == 0)  um1 = 0.f;
        float up4 = __shfl_down(u.x, 1, 64); if (tx == 31) up4 = 0.f;
        float vm1 = __shfl_up(v.w, 1, 64);   if (tx == 0)  vm1 = 0.f;
        float vp4 = __shfl_down(v.x, 1, 64); if (tx == 31) vp4 = 0.f;
        cc.x = um1 + 2.f * u.x + u.y;
        cc.y = u.x + 2.f * u.y + u.z;
        cc.z = u.y + 2.f * u.z + u.w;
        cc.w = u.z + 2.f * u.w + up4;
        ee.x = um1 - u.y;                 // Dx(u): reuses u's shuffled halos
        ee.y = u.x - u.z;
        ee.z = u.y - u.w;
        ee.w = u.z - up4;
        dd.x = vm1 + 2.f * v.x + v.y;
        dd.y = v.x + 2.f * v.y + v.z;
        dd.z = v.y + 2.f * v.z + v.w;
        dd.w = v.z + 2.f * v.w + vp4;
    };

    // rolling 2-plane intermediates: P = plane z-1, C = plane z
    floatx4 cP, dP, eP, cC, dCv, eC;
    const float* pin = xp + (size_t)za * HW + roff;   // plane za
    {
        floatx4 a, bq, c;
        if (za > 0) { load3(pin - HW, a, bq, c); plane_sde(a, bq, c, cP, dP, eP); }
        else        { cP = dP = eP = (floatx4){0.f, 0.f, 0.f, 0.f}; }
        load3(pin, a, bq, c); plane_sde(a, bq, c, cC, dCv, eC);
    }
    // depth-2 prefetch: p = rows of plane za+1, q = rows of plane za+2
    floatx4 pA, pB, pC, qA, qB, qC;
    load3(pin + HW,     pA, pB, pC);
    load3(pin + 2 * HW, qA, qB, qC);
    const float* plast = pin + (size_t)(lastv - za) * HW;  // last valid plane ptr
    pin += 3 * HW;                                         // -> plane za+3
    float* pout = op + (size_t)za * HW + roff;

    for (int z = za; z < zb; ++z) {
        // prefetch plane z+3, branch-free: clamp to last valid plane (its rows
        // are L2-hot; re-reading them beats a control-flow merge). The clamped
        // values are consumed only by iterations whose outputs don't use them.
        const float* pf = (z + 3 <= lastv) ? pin : plast;
        floatx4 nA, nB, nC;
        load3(pf, nA, nB, nC);
        pin += HW;

        // compute plane z+1 intermediates (rows prefetched 2 iterations ago)
        floatx4 c2, d2, e2;
        plane_sde(pA, pB, pC, c2, d2, e2);

        // z-combine needs plane z+1 = zb at the last iter (z=zb-1): correct,
        // because p then holds plane zb's rows when zb<DZ, or plane DZ-1's
        // clamped rows only when zb==DZ... zb==DZ needs zeros, not clamp:
        // handled below by masking e2/d2/c2 on the final global plane.
        if (z == DZ - 1) { c2 = d2 = e2 = (floatx4){0.f, 0.f, 0.f, 0.f}; }

        // emit output plane z
        floatx4 gx = eP + 2.f * eC + e2;
        floatx4 gy = dP + 2.f * dCv + d2;
        floatx4 gz = cP - c2;
        floatx4 o;
        o.x = __builtin_amdgcn_sqrtf(gx.x * gx.x + gy.x * gy.x + gz.x * gz.x + 1e-6f);
        o.y = __builtin_amdgcn_sqrtf(gx.y * gx.y + gy.y * gy.y + gz.y * gz.y + 1e-6f);
        o.z = __builtin_amdgcn_sqrtf(gx.z * gx.z + gy.z * gy.z + gz.z * gz.z + 1e-6f);
        o.w = __builtin_amdgcn_sqrtf(gx.w * gx.w + gy.w * gy.w + gz.w * gz.w + 1e-6f);
        __builtin_nontemporal_store(o, (floatx4*)pout);
        pout += HW;

        // roll windows
        cP = cC;  cC  = c2;
        dP = dCv; dCv = d2;
        eP = eC;  eC  = e2;
        pA = qA;  pB  = qB;  pC = qC;
        qA = nA;  qB  = nB;  qC = nC;
    }
}

extern "C" void kernel_launch(void* const* d_in, const int* in_sizes, int n_in,
                              void* d_out, int out_size, void* d_ws, size_t ws_size,
                              hipStream_t stream) {
    const float* x = (const float*)d_in[0];
    float* out = (float*)d_out;
    dim3 grid(NC * ZCH * HBLKS);   // 2048 blocks == full 8-blocks/CU residency
    dim3 block(256);
    sobel3d_kernel<<<grid, block, 0, stream>>>(x, out);
}

// Round 11
// 96.435 us; speedup vs baseline: 1.9432x; 1.1168x over previous
//
#include <hip/hip_runtime.h>

// Sobel 3D magnitude, separable: S=[1,2,1], D=[1,0,-1]
// gx = Sz(Sy(Dx)), gy = Sz(Dy(Sx)), gz = Dz(Sy(Sx)); out = sqrt(gx^2+gy^2+gz^2+1e-6)
// x: (2,32,64,128,128) fp32.
// FINAL = R7 (best of 10 rounds, 96.6 us):
//   - no LDS, no barriers: each thread reads rows h-1,h,h+1 directly from
//     global; L1/L2/L3 absorb the 3x row overlap between adjacent-ty threads.
//   - y-pass-first separable order: u=Sy(x) (no shuffles), v=Dy(x); the x-pass
//     derives Sx/Dx from u,v with only 4 shuffles/plane (Dx reuses Sx halos).
//   - depth-1 register prefetch of plane z+2 rows; marching pointers (no
//     per-iter 64-bit recompute); wave-uniform scalar branch on prefetch
//     validity; nontemporal float4 output stores.
//   - 2048 blocks == full 8-blocks/CU residency (z split in 2 chunks),
//     launch_bounds(256,6): compiles to 36 VGPR, zero spill.
// Falsified alternatives: LDS staging + barriers (R1-R4: barrier drain +
// launch_bounds(256,8) forces 32-VGPR spill), lane^32 row sharing (R8: adds
// shuffle to the load critical path), depth-2 prefetch (R6/R9 spill; R10
// clean but slower - latency depth is not the limiter).

typedef float floatx4 __attribute__((ext_vector_type(4)));

constexpr int W   = 128;
constexpr int H   = 128;
constexpr int DZ  = 64;
constexpr int NC  = 2 * 32;
constexpr int TH  = 8;            // output rows per block
constexpr int HBLKS = H / TH;     // 16
constexpr int ZCH = 2;            // z chunks
constexpr int ZLEN = DZ / ZCH;    // 32

__global__ __launch_bounds__(256, 6)
void sobel3d_kernel(const float* __restrict__ xg, float* __restrict__ og) {
    const int tid = threadIdx.x;
    const int tx  = tid & 31;      // w segment: pixels 4*tx..4*tx+3
    const int ty  = tid >> 5;      // row 0..7 within tile
    int b = blockIdx.x;
    const int hblk = b % HBLKS; b /= HBLKS;
    const int zc   = b % ZCH;   b /= ZCH;
    const int nc   = b;
    const int h    = hblk * TH + ty;
    const int za   = zc * ZLEN;
    const int zb   = za + ZLEN;                  // exclusive
    const int lastv = (zb < DZ) ? zb : DZ - 1;   // last loadable plane index

    const size_t HW = (size_t)H * W;
    const float* __restrict__ xp = xg + (size_t)nc * DZ * HW;
    float* __restrict__ op       = og + (size_t)nc * DZ * HW;

    const bool hm = (h > 0);
    const bool hp = (h < H - 1);
    const size_t roff = (size_t)h * W + 4 * tx;

    // rows h-1,h,h+1 at pointer p (p = plane base + roff); ±W fold to imm offsets
    auto load3 = [&](const float* p, floatx4& a, floatx4& bq, floatx4& c) {
        a  = hm ? *(const floatx4*)(p - W) : (floatx4){0.f, 0.f, 0.f, 0.f};
        bq = *(const floatx4*)p;
        c  = hp ? *(const floatx4*)(p + W) : (floatx4){0.f, 0.f, 0.f, 0.f};
    };

    // y-pass first (no shuffles), then x-pass on u=Sy(x), v=Dy(x).
    // cc = Sx(Sy), dd = Sx(Dy) = Dy(Sx), ee = Dx(Sy) = Sy(Dx)  (axes commute)
    auto plane_sde = [&](floatx4 qA, floatx4 qB, floatx4 qC,
                         floatx4& cc, floatx4& dd, floatx4& ee) {
        floatx4 u = qA + 2.f * qB + qC;
        floatx4 v = qA - qC;
        float um1 = __shfl_up(u.w, 1, 64);   if (tx == 0)  um1 = 0.f;
        float up4 = __shfl_down(u.x, 1, 64); if (tx == 31) up4 = 0.f;
        float vm1 = __shfl_up(v.w, 1, 64);   if (tx == 0)  vm1 = 0.f;
        float vp4 = __shfl_down(v.x, 1, 64); if (tx == 31) vp4 = 0.f;
        cc.x = um1 + 2.f * u.x + u.y;
        cc.y = u.x + 2.f * u.y + u.z;
        cc.z = u.y + 2.f * u.z + u.w;
        cc.w = u.z + 2.f * u.w + up4;
        ee.x = um1 - u.y;                 // Dx(u): reuses u's shuffled halos
        ee.y = u.x - u.z;
        ee.z = u.y - u.w;
        ee.w = u.z - up4;
        dd.x = vm1 + 2.f * v.x + v.y;
        dd.y = v.x + 2.f * v.y + v.z;
        dd.z = v.y + 2.f * v.z + v.w;
        dd.w = v.z + 2.f * v.w + vp4;
    };

    // rolling 2-plane intermediates: P = plane z-1, C = plane z
    floatx4 cP, dP, eP, cC, dCv, eC;
    const float* pin = xp + (size_t)za * HW + roff;   // plane za
    {
        floatx4 a, bq, c;
        if (za > 0) { load3(pin - HW, a, bq, c); plane_sde(a, bq, c, cP, dP, eP); }
        else        { cP = dP = eP = (floatx4){0.f, 0.f, 0.f, 0.f}; }
        load3(pin, a, bq, c); plane_sde(a, bq, c, cC, dCv, eC);
    }
    // depth-1 prefetch: raw rows of plane za+1 (always valid: za+1 <= 33 < DZ)
    floatx4 pA, pB, pC;
    load3(pin + HW, pA, pB, pC);
    pin += 2 * HW;                                    // -> plane za+2
    float* pout = op + (size_t)za * HW + roff;

#pragma unroll 2
    for (int z = za; z < zb; ++z) {
        // prefetch plane z+2 (wave-uniform validity -> scalar branch, no fetch past need)
        floatx4 nA, nB, nC;
        if (z + 2 <= lastv) load3(pin, nA, nB, nC);
        else { nA = nB = nC = (floatx4){0.f, 0.f, 0.f, 0.f}; }
        pin += HW;

        // compute plane z+1 intermediates from rows prefetched last iteration
        floatx4 c2, d2, e2;
        plane_sde(pA, pB, pC, c2, d2, e2);

        // emit output plane z
        floatx4 gx = eP + 2.f * eC + e2;
        floatx4 gy = dP + 2.f * dCv + d2;
        floatx4 gz = cP - c2;
        floatx4 o;
        o.x = __builtin_amdgcn_sqrtf(gx.x * gx.x + gy.x * gy.x + gz.x * gz.x + 1e-6f);
        o.y = __builtin_amdgcn_sqrtf(gx.y * gx.y + gy.y * gy.y + gz.y * gz.y + 1e-6f);
        o.z = __builtin_amdgcn_sqrtf(gx.z * gx.z + gy.z * gy.z + gz.z * gz.z + 1e-6f);
        o.w = __builtin_amdgcn_sqrtf(gx.w * gx.w + gy.w * gy.w + gz.w * gz.w + 1e-6f);
        __builtin_nontemporal_store(o, (floatx4*)pout);
        pout += HW;

        // roll windows (renamed away by the unroll)
        cP = cC;  cC  = c2;
        dP = dCv; dCv = d2;
        eP = eC;  eC  = e2;
        pA = nA;  pB  = nB;  pC = nC;
    }
}

extern "C" void kernel_launch(void* const* d_in, const int* in_sizes, int n_in,
                              void* d_out, int out_size, void* d_ws, size_t ws_size,
                              hipStream_t stream) {
    const float* x = (const float*)d_in[0];
    float* out = (float*)d_out;
    dim3 grid(NC * ZCH * HBLKS);   // 2048 blocks == full 8-blocks/CU residency
    dim3 block(256);
    sobel3d_kernel<<<grid, block, 0, stream>>>(x, out);
}